// Round 6
// baseline (366.630 us; speedup 1.0000x reference)
//
#include <hip/hip_runtime.h>
#include <hip/hip_bf16.h>
#include <stdint.h>

#define N_NODES 50000
#define MPAD    50048          // 782 * 64
#define EDGES   800000
#define EPRIME  (EDGES + N_NODES)
#define NGRAPH  64
#define GN_EPS  1e-5f
#define ECPAD   53248          // 208 * 256, >= N_NODES
#define NBLK    208

typedef __attribute__((ext_vector_type(8))) short short8;
typedef __attribute__((ext_vector_type(4))) float floatx4;
typedef __attribute__((ext_vector_type(2))) float float2v;

__device__ __forceinline__ uint32_t pk2bf(float a, float b) {
    union { __hip_bfloat162 h; uint32_t u; } cv;
    cv.h = __float22bfloat162_rn(make_float2(a, b));
    return cv.u;
}

__device__ __forceinline__ unsigned short f2b(float f) {
    uint32_t u = __float_as_uint(f);
    u += 0x7fffu + ((u >> 16) & 1u);   // RTNE
    return (unsigned short)(u >> 16);
}

// ---------- fused: Wt transpose-convert (blocks 0..255) + histograms ----------
__global__ __launch_bounds__(512) void k_prep(const float* __restrict__ Wl,
                                              const float* __restrict__ Wr,
                                              unsigned short* __restrict__ Wt,
                                              const int* __restrict__ ei,
                                              const int* __restrict__ batch,
                                              int* __restrict__ ecount,
                                              int* __restrict__ ncount,
                                              int* __restrict__ sedge) {
    __shared__ int hist[NGRAPH];
    int b = blockIdx.x;
    int t = threadIdx.x;
    if (b < 256) {                      // Wt[n][k] = W[k][n] bf16; n>=256 -> W_r
        int idx = b * 512 + t;          // 131072 total
        int n = idx >> 8, k = idx & 255;
        float v = (n < 256) ? Wl[k * 256 + n] : Wr[k * 256 + (n - 256)];
        Wt[idx] = f2b(v);
        return;
    }
    if (t < NGRAPH) hist[t] = 0;
    __syncthreads();
    int e = (b - 256) * 512 + t;
    if (e < EPRIME) {
        int d = (e < EDGES) ? ei[EDGES + e] : (e - EDGES);
        atomicAdd(&ecount[d], 1);
    }
    if (e < N_NODES) atomicAdd(&hist[batch[e]], 1);
    if (b == 256 && t < 16) sedge[EPRIME + t] = 0;   // tail pad for k_msg prefetch
    __syncthreads();
    if (t < NGRAPH && hist[t]) atomicAdd(&ncount[t], hist[t]);
}

// ---------- GEMM: [XL|XR] = bf16(x) @ [W_l|W_r] ----------
__global__ __launch_bounds__(512) void k_gemm(const float* __restrict__ x,
                                              const unsigned short* __restrict__ Wt,
                                              const float* __restrict__ bl,
                                              const float* __restrict__ br,
                                              unsigned short* __restrict__ XL,
                                              unsigned short* __restrict__ XR) {
    __shared__ unsigned short As[64 * 256];       // 32 KB
    int rbase = blockIdx.x * 64;
    int tid = threadIdx.x;

#pragma unroll
    for (int it = 0; it < 4; ++it) {
        int c = it * 512 + tid;
        int row = c >> 5, ch = c & 31;
        int gr = rbase + row;
        float4 f0, f1;
        if (gr < N_NODES) {
            const float4* src = (const float4*)(x + (size_t)gr * 256 + ch * 8);
            f0 = src[0]; f1 = src[1];
        } else {
            f0 = make_float4(0.f,0.f,0.f,0.f); f1 = f0;
        }
        uint4 hv = make_uint4(pk2bf(f0.x, f0.y), pk2bf(f0.z, f0.w),
                              pk2bf(f1.x, f1.y), pk2bf(f1.z, f1.w));
        *(uint4*)(As + row * 256 + (ch ^ (row & 7)) * 8) = hv;
    }
    __syncthreads();

    int w = tid >> 6;
    int l = tid & 63;
    int m = l & 15, q = l >> 4;

    floatx4 acc[4][4];
#pragma unroll
    for (int rf = 0; rf < 4; ++rf)
#pragma unroll
        for (int cf = 0; cf < 4; ++cf)
            acc[rf][cf] = (floatx4){0.f, 0.f, 0.f, 0.f};

    const unsigned short* wbase = Wt + (size_t)(w * 64) * 256;

#pragma unroll
    for (int kk = 0; kk < 8; ++kk) {
        // global B loads first so their latency overlaps the LDS reads
        short8 b[4];
#pragma unroll
        for (int cf = 0; cf < 4; ++cf)
            b[cf] = *(const short8*)(wbase + (size_t)(cf * 16 + m) * 256 + kk * 32 + q * 8);
        short8 a[4];
#pragma unroll
        for (int rf = 0; rf < 4; ++rf) {
            int row = rf * 16 + m;
            int ch = (kk * 4 + q) ^ (row & 7);
            a[rf] = *(const short8*)(As + row * 256 + ch * 8);
        }
#pragma unroll
        for (int cf = 0; cf < 4; ++cf)
#pragma unroll
            for (int rf = 0; rf < 4; ++rf)   // A-slot = W frag -> D = C^T tile
                acc[rf][cf] = __builtin_amdgcn_mfma_f32_16x16x32_bf16(b[cf], a[rf], acc[rf][cf], 0, 0, 0);
    }

    // D layout (transposed compute): node = lane&15, channel = q*4 + reg.
    unsigned short* obase = (w < 4) ? XL : XR;
    const float* bptr = (w < 4) ? bl : br;
    int cb = (w & 3) * 64;
#pragma unroll
    for (int cf = 0; cf < 4; ++cf) {
        int chb = cb + cf * 16 + q * 4;
        float4 bv = *(const float4*)(bptr + chb);
#pragma unroll
        for (int rf = 0; rf < 4; ++rf) {
            int node = rbase + rf * 16 + m;
            uint2 o;
            o.x = pk2bf(acc[rf][cf][0] + bv.x, acc[rf][cf][1] + bv.y);
            o.y = pk2bf(acc[rf][cf][2] + bv.z, acc[rf][cf][3] + bv.w);
            *(uint2*)(obase + (size_t)node * 256 + chb) = o;  // pad rows exist
        }
    }
}

// ---------- scan phase 1+2: per-block sums; last block scans the 208 sums ----------
__global__ __launch_bounds__(256) void k_scan1(const int* __restrict__ ecount,
                                               int* __restrict__ bsum,
                                               int* __restrict__ ticket) {
    __shared__ int red[256];
    __shared__ int buf[256];
    __shared__ int amlast;
    int t = threadIdx.x;
    int v = ecount[blockIdx.x * 256 + t];
    red[t] = v;
    __syncthreads();
    for (int off = 128; off > 0; off >>= 1) {
        if (t < off) red[t] += red[t + off];
        __syncthreads();
    }
    if (t == 0) {
        __hip_atomic_store(&bsum[blockIdx.x], red[0], __ATOMIC_RELEASE, __HIP_MEMORY_SCOPE_AGENT);
        int tk = __hip_atomic_fetch_add(ticket, 1, __ATOMIC_ACQ_REL, __HIP_MEMORY_SCOPE_AGENT);
        amlast = (tk == NBLK - 1);
    }
    __syncthreads();
    if (amlast) {
        int bv = (t < NBLK) ? __hip_atomic_load(&bsum[t], __ATOMIC_ACQUIRE, __HIP_MEMORY_SCOPE_AGENT) : 0;
        buf[t] = bv;
        __syncthreads();
        for (int off = 1; off < 256; off <<= 1) {
            int p = (t >= off) ? buf[t - off] : 0;
            __syncthreads();
            buf[t] += p;
            __syncthreads();
        }
        if (t < NBLK) bsum[t] = buf[t] - bv;     // exclusive block offsets
    }
}

// ---------- scan phase 3: per-element exclusive positions ----------
__global__ __launch_bounds__(256) void k_scan3(const int* __restrict__ ecount,
                                               const int* __restrict__ bsum,
                                               int* __restrict__ estart,
                                               int* __restrict__ ecursor) {
    __shared__ int buf[256];
    int b = blockIdx.x, t = threadIdx.x;
    int v = ecount[b * 256 + t];
    buf[t] = v;
    __syncthreads();
    for (int off = 1; off < 256; off <<= 1) {
        int p = (t >= off) ? buf[t - off] : 0;
        __syncthreads();
        buf[t] += p;
        __syncthreads();
    }
    int e = bsum[b] + buf[t] - v;
    estart[b * 256 + t]  = e;
    ecursor[b * 256 + t] = e;
}

// ---------- scatter edges into dst-sorted order (store src only) ----------
__global__ __launch_bounds__(256) void k_scatter(const int* __restrict__ ei,
                                                 int* __restrict__ ecursor,
                                                 int* __restrict__ sedge) {
    int e = blockIdx.x * 256 + threadIdx.x;
    if (e >= EPRIME) return;
    int s, d;
    if (e < EDGES) { s = ei[e]; d = ei[EDGES + e]; }
    else           { s = d = e - EDGES; }
    int pos = atomicAdd(&ecursor[d], 1);
    sedge[pos] = s;
}

// ---------- core: one wave per dst, packed f32 math, 4-edge pipeline ----------
__global__ __launch_bounds__(256) void k_msg(const unsigned short* __restrict__ XL,
                                             const unsigned short* __restrict__ XRb,
                                             const float* __restrict__ x,
                                             const float* __restrict__ att,
                                             const float* __restrict__ bias,
                                             const int* __restrict__ sedge,
                                             const int* __restrict__ estart,
                                             const int* __restrict__ ecount,
                                             float* __restrict__ out) {
    int d = (int)((blockIdx.x * 256 + threadIdx.x) >> 6);
    int l = threadIdx.x & 63;
    int lofs = l * 8;                 // byte offset of this lane's uint2 in a row

    float4 xin  = ((const float4*)(x + (size_t)d * 256))[l];
    float4 bvv  = ((const float4*)bias)[l];
    float4 attv = ((const float4*)att)[l];
    float2v att01 = {attv.x, attv.y}, att23 = {attv.z, attv.w};

    uint2 xru = ((const uint2*)(XRb + (size_t)d * 256))[l];
    float2v xr01, xr23;
    xr01[0] = __uint_as_float(xru.x << 16);
    xr01[1] = __uint_as_float(xru.x & 0xffff0000u);
    xr23[0] = __uint_as_float(xru.y << 16);
    xr23[1] = __uint_as_float(xru.y & 0xffff0000u);

    int s0  = __builtin_amdgcn_readfirstlane(estart[d]);
    int cnt = __builtin_amdgcn_readfirstlane(ecount[d]);

    auto ldrow = [&](int src) -> uint2 {
        size_t off = ((size_t)(uint32_t)__builtin_amdgcn_readfirstlane(src)) << 9;
        return *(const uint2*)((const char*)XL + off + lofs);
    };

    float den0 = 0.f, den1 = 0.f, den2 = 0.f, den3 = 0.f;
    float2v A01 = {0.f,0.f}, A23 = {0.f,0.f};
    float2v B01 = {0.f,0.f}, B23 = {0.f,0.f};
    float2v C01 = {0.f,0.f}, C23 = {0.f,0.f};
    float2v D01 = {0.f,0.f}, D23 = {0.f,0.f};

    // MASKED==false quads are fully valid; tail quad masks alpha to 0 per slot.
#define PROC(U, VALID, DEN, R01, R23)                                        \
    {                                                                        \
        float2v x01, x23;                                                    \
        x01[0] = __uint_as_float(U.x << 16);                                 \
        x01[1] = __uint_as_float(U.x & 0xffff0000u);                         \
        x23[0] = __uint_as_float(U.y << 16);                                 \
        x23[1] = __uint_as_float(U.y & 0xffff0000u);                         \
        float2v e01 = x01 + xr01, e23 = x23 + xr23;                          \
        e01 = __builtin_elementwise_max(e01, e01 * 0.2f);                    \
        e23 = __builtin_elementwise_max(e23, e23 * 0.2f);                    \
        float2v pp2 = __builtin_elementwise_fma(e23, att23, e01 * att01);    \
        float pp = pp2[0] + pp2[1];                                          \
        int pi = __float_as_int(pp);                                         \
        pp += __int_as_float(__builtin_amdgcn_update_dpp(0, pi, 0xB1, 0xF, 0xF, true)); \
        pi = __float_as_int(pp);                                             \
        pp += __int_as_float(__builtin_amdgcn_update_dpp(0, pi, 0x4E, 0xF, 0xF, true)); \
        pp += __int_as_float(__builtin_amdgcn_ds_swizzle(__float_as_int(pp), 0x101F)); \
        float al = __expf(fminf(pp, 80.f));                                  \
        al = (VALID) ? al : 0.f;                                             \
        DEN += al;                                                           \
        float2v al2 = {al, al};                                              \
        R01 = __builtin_elementwise_fma(al2, x01, R01);                      \
        R23 = __builtin_elementwise_fma(al2, x23, R23);                      \
    }

    // fill: slots 0..3 (sedge tail-padded with 16 zeros -> always safe)
    uint2 P0 = ldrow(sedge[s0]);
    uint2 P1 = ldrow(sedge[s0 + 1]);
    uint2 P2 = ldrow(sedge[s0 + 2]);
    uint2 P3 = ldrow(sedge[s0 + 3]);

    int nq = (cnt + 3) >> 2;          // >= 1 (self-loop guarantees cnt >= 1)
    for (int qq = 0; qq < nq - 1; ++qq) {
        uint2 Q0 = P0, Q1 = P1, Q2 = P2, Q3 = P3;
        int nb = s0 + (qq + 1) * 4;
        P0 = ldrow(sedge[nb]);
        P1 = ldrow(sedge[nb + 1]);
        P2 = ldrow(sedge[nb + 2]);
        P3 = ldrow(sedge[nb + 3]);
        PROC(Q0, true, den0, A01, A23);
        PROC(Q1, true, den1, B01, B23);
        PROC(Q2, true, den2, C01, C23);
        PROC(Q3, true, den3, D01, D23);
    }
    {   // tail quad: slots base..base+3, alpha-masked
        int base = (nq - 1) * 4;
        PROC(P0, base + 0 < cnt, den0, A01, A23);
        PROC(P1, base + 1 < cnt, den1, B01, B23);
        PROC(P2, base + 2 < cnt, den2, C01, C23);
        PROC(P3, base + 3 < cnt, den3, D01, D23);
    }
#undef PROC

    float inv = 1.f / ((den0 + den1) + (den2 + den3) + 1e-16f);
    A01 = (A01 + B01) + (C01 + D01);
    A23 = (A23 + B23) + (C23 + D23);

    float h0 = A01[0] * inv + bvv.x + xin.x; h0 = (h0 > 0.f) ? h0 : (__expf(h0) - 1.f);
    float h1 = A01[1] * inv + bvv.y + xin.y; h1 = (h1 > 0.f) ? h1 : (__expf(h1) - 1.f);
    float h2 = A23[0] * inv + bvv.z + xin.z; h2 = (h2 > 0.f) ? h2 : (__expf(h2) - 1.f);
    float h3 = A23[1] * inv + bvv.w + xin.w; h3 = (h3 > 0.f) ? h3 : (__expf(h3) - 1.f);
    ((float4*)(out + (size_t)d * 256))[l] = make_float4(h0, h1, h2, h3);
}

// ---------- GraphNorm stats: 64-row blocks, 4-row unrolled fast path ----------
#define GN_ROWS 64
__global__ __launch_bounds__(256) void k_gn_sum(const float* __restrict__ h,
                                                const int* __restrict__ batch,
                                                float* __restrict__ gsum,
                                                float* __restrict__ gsq) {
    __shared__ int bsh[GN_ROWS];
    int r0 = blockIdx.x * GN_ROWS;
    if (threadIdx.x < GN_ROWS) {
        int i = r0 + threadIdx.x;
        bsh[threadIdx.x] = (i < N_NODES) ? batch[i] : -1;
    }
    __syncthreads();
    int c = threadIdx.x;
    float s1 = 0.f, s2 = 0.f;
    int g = bsh[0];
    for (int j = 0; j < GN_ROWS; j += 4) {
        int i = r0 + j;
        if (i >= N_NODES) break;
        bool full = (i + 3 < N_NODES);
        if (full && bsh[j] == g && bsh[j + 3] == g) {
            const float* hp = h + (size_t)i * 256 + c;
            float v0 = hp[0], v1 = hp[256], v2 = hp[512], v3 = hp[768];
            s1 += (v0 + v1) + (v2 + v3);
            s2 += (v0 * v0 + v1 * v1) + (v2 * v2 + v3 * v3);
        } else {
            for (int jj = j; jj < j + 4; ++jj) {
                int ii = r0 + jj;
                if (ii >= N_NODES) break;
                int bg = bsh[jj];
                if (bg != g) {
                    atomicAdd(&gsum[g * 256 + c], s1);
                    atomicAdd(&gsq[g * 256 + c], s2);
                    s1 = 0.f; s2 = 0.f; g = bg;
                }
                float v = h[(size_t)ii * 256 + c];
                s1 += v; s2 += v * v;
            }
        }
    }
    atomicAdd(&gsum[g * 256 + c], s1);
    atomicAdd(&gsq[g * 256 + c], s2);
}

// ---------- GraphNorm finalize: var = E[h^2] - m^2 * s * (2 - s) ----------
__global__ __launch_bounds__(256) void k_final(float* __restrict__ out,
                                               const int* __restrict__ batch,
                                               const float* __restrict__ gsum,
                                               const float* __restrict__ gsq,
                                               const int* __restrict__ ncount,
                                               const float* __restrict__ gnw,
                                               const float* __restrict__ gnb,
                                               const float* __restrict__ gms) {
    int idx = blockIdx.x * 256 + threadIdx.x;
    int i = idx >> 6, l = idx & 63;
    if (i >= N_NODES) return;
    int g = batch[i];
    float inv = 1.f / fmaxf((float)ncount[g], 1.f);
    float4 hv = ((const float4*)(out + (size_t)i * 256))[l];
    float4 ms = ((const float4*)(gsum + g * 256))[l];
    float4 qs = ((const float4*)(gsq  + g * 256))[l];
    float4 wv = ((const float4*)gnw)[l];
    float4 bv = ((const float4*)gnb)[l];
    float4 sv = ((const float4*)gms)[l];
    float4 o;
    {
        float m = ms.x * inv, q = qs.x * inv;
        o.x = wv.x * (hv.x - sv.x * m) * rsqrtf(q - m * m * sv.x * (2.f - sv.x) + GN_EPS) + bv.x;
    }
    {
        float m = ms.y * inv, q = qs.y * inv;
        o.y = wv.y * (hv.y - sv.y * m) * rsqrtf(q - m * m * sv.y * (2.f - sv.y) + GN_EPS) + bv.y;
    }
    {
        float m = ms.z * inv, q = qs.z * inv;
        o.z = wv.z * (hv.z - sv.z * m) * rsqrtf(q - m * m * sv.z * (2.f - sv.z) + GN_EPS) + bv.z;
    }
    {
        float m = ms.w * inv, q = qs.w * inv;
        o.w = wv.w * (hv.w - sv.w * m) * rsqrtf(q - m * m * sv.w * (2.f - sv.w) + GN_EPS) + bv.w;
    }
    ((float4*)(out + (size_t)i * 256))[l] = o;
}

extern "C" void kernel_launch(void* const* d_in, const int* in_sizes, int n_in,
                              void* d_out, int out_size, void* d_ws, size_t ws_size,
                              hipStream_t stream) {
    const float* x    = (const float*)d_in[0];
    const int*   ei   = (const int*)d_in[1];
    const int*   batch= (const int*)d_in[2];
    const float* Wl   = (const float*)d_in[3];
    const float* bl   = (const float*)d_in[4];
    const float* Wr   = (const float*)d_in[5];
    const float* br   = (const float*)d_in[6];
    const float* att  = (const float*)d_in[7];
    const float* bias = (const float*)d_in[8];
    const float* gnw  = (const float*)d_in[9];
    const float* gnb  = (const float*)d_in[10];
    const float* gms  = (const float*)d_in[11];
    float* out = (float*)d_out;

    char* p = (char*)d_ws;
    auto alloc = [&](size_t bytes) -> char* {
        char* r = p;
        p += (bytes + 255) & ~(size_t)255;
        return r;
    };
    unsigned short* Wt  = (unsigned short*)alloc((size_t)512 * 256 * 2);
    unsigned short* XL  = (unsigned short*)alloc((size_t)MPAD * 256 * 2);
    unsigned short* XRb = (unsigned short*)alloc((size_t)MPAD * 256 * 2);
    int* estart         = (int*)alloc((size_t)ECPAD * 4);
    int* ecursor        = (int*)alloc((size_t)ECPAD * 4);
    int* sedge          = (int*)alloc((size_t)(EPRIME + 16) * 4);
    int* bsum           = (int*)alloc((size_t)256 * 4);
    // ---- contiguous zero-init region: ecount | ncount | ticket | gsum | gsq ----
    int* ecount         = (int*)alloc((size_t)ECPAD * 4);
    int* ncount         = (int*)alloc((size_t)NGRAPH * 4);
    int* ticket         = (int*)alloc((size_t)64 * 4);
    float* gsum         = (float*)alloc((size_t)2 * NGRAPH * 256 * 4);  // gsum || gsq
    float* gsq          = gsum + NGRAPH * 256;
    size_t zbytes = (size_t)((char*)(gsum + 2 * NGRAPH * 256) - (char*)ecount);
    hipMemsetAsync(ecount, 0, zbytes, stream);

    k_prep<<<256 + (EPRIME + 511) / 512, 512, 0, stream>>>(Wl, Wr, Wt, ei, batch,
                                                           ecount, ncount, sedge);
    k_gemm<<<MPAD / 64, 512, 0, stream>>>(x, Wt, bl, br, XL, XRb);

    k_scan1<<<NBLK, 256, 0, stream>>>(ecount, bsum, ticket);
    k_scan3<<<NBLK, 256, 0, stream>>>(ecount, bsum, estart, ecursor);
    k_scatter<<<(EPRIME + 255) / 256, 256, 0, stream>>>(ei, ecursor, sedge);

    k_msg<<<N_NODES / 4, 256, 0, stream>>>(XL, XRb, x, att, bias,
                                           sedge, estart, ecount, out);

    k_gn_sum<<<(N_NODES + GN_ROWS - 1) / GN_ROWS, 256, 0, stream>>>(out, batch, gsum, gsq);
    k_final<<<N_NODES * 64 / 256, 256, 0, stream>>>(out, batch, gsum, gsq,
                                                    ncount, gnw, gnb, gms);
}